// Round 17
// baseline (308.554 us; speedup 1.0000x reference)
//
#include <hip/hip_runtime.h>
#include <math.h>

// GConvLSTM single step from zero state + linear head.
// H=C=0 initially => cheb_conv(H)=bh[g], F-gate irrelevant.
//   I = sigmoid(chebX_0 + b*), T = tanh(chebX_2 + b*), C = I*T,
//   O = sigmoid(chebX_3 + b* + wc2*C), out = (O*tanh(C)) @ lin_w + lin_b
//
// R2 pull-CSR; R3 hw transcendentals; R7 zero global atomics;
// R8 bf16 MFMA; R9 bf16 recursion; R10 fused gather3; R11 full-CU scans;
// R12 merged scan w/ atomic barrier; R13/R14 operand-split front + fill.
// R15/R16 (FAILED): mega-kernel fusion forced gathers to the MFMA phase's
//      128-VGPR allocation (21% occupancy, 115us).
// R17: R14 base + fuse ONLY the register-footprint-matched gather pair
//      (k_gather12, launch_bounds(256,8) VGPR<=64, 2048 co-resident blocks,
//      one cheap in-kernel barrier) + flags memset folded into k_front.
//      Dispatches 8 -> 5.

#define NT 256
#define NCH 64      // edge chunks
#define RSD 25600   // deg hist range: 25600*4B = 100KB LDS
#define RSF 20480   // fill range: 80KB LDS
#define G12 2048    // fused gather grid: 8 blocks/CU x 256 CUs (co-resident)
#define NT12 256

typedef __attribute__((ext_vector_type(8))) short short8v;
typedef __attribute__((ext_vector_type(8))) unsigned short ushort8v;
typedef __attribute__((ext_vector_type(4))) float f32x4;

__device__ __forceinline__ short f2bf(float f) {
    unsigned u = __float_as_uint(f);
    u += 0x7FFFu + ((u >> 16) & 1u);   // round-to-nearest-even
    return (short)(u >> 16);
}
__device__ __forceinline__ float bf2f(unsigned short b) {
    return __uint_as_float((unsigned)b << 16);
}

// grid barrier, cheap form: one release-add + relaxed spin + one acquire
// fence per BLOCK (not per thread, not per spin iteration).
__device__ __forceinline__ void gbar(int* flag, int target) {
    __syncthreads();
    if (threadIdx.x == 0) {
        __hip_atomic_fetch_add(flag, 1, __ATOMIC_RELEASE, __HIP_MEMORY_SCOPE_AGENT);
        while (__hip_atomic_load(flag, __ATOMIC_RELAXED,
                                 __HIP_MEMORY_SCOPE_AGENT) < target)
            __builtin_amdgcn_s_sleep(8);
        __builtin_amdgcn_fence(__ATOMIC_ACQUIRE, "agent");
    }
    __syncthreads();
}

// K1: role A (bid < degB): deg f32 LDS histogram (2 ranges x 64 chunks).
// role B (next 64): cnt u16-packed whole-N histogram. role C: prepack + xb.
// Block 0 also zeroes the barrier flags (visible to later kernels by
// stream order).
__global__ __launch_bounds__(1024)
void k_front(const int* __restrict__ src, const int* __restrict__ dst,
             const float* __restrict__ w, float* __restrict__ degPart,
             unsigned short* __restrict__ cntPart,
             const float* __restrict__ Wx, short* __restrict__ P,
             const float* __restrict__ x, short* __restrict__ xb,
             int* __restrict__ flags, int nE, int N, int degB, int n4) {
    __shared__ unsigned smem[RSD];   // 100KB, role-dependent view
    const int bid = blockIdx.x;
    const int chunk = (nE + NCH - 1) / NCH;
    if (bid == 0 && threadIdx.x < 2) flags[threadIdx.x] = 0;

    if (bid < degB) {                       // ---- deg histogram ----
        float* s_deg = reinterpret_cast<float*>(smem);
        const int r = bid / NCH, b = bid % NCH;
        const int base = r * RSD;
        for (int i = threadIdx.x; i < RSD; i += 1024) s_deg[i] = 0.f;
        __syncthreads();
        const int e0 = b * chunk, e1 = min(e0 + chunk, nE);
        for (int e = e0 + (int)threadIdx.x; e < e1; e += 1024) {
            unsigned so = (unsigned)(src[e] - base);
            if (so < RSD) atomicAdd(&s_deg[so], w[e]);
        }
        __syncthreads();
        const int lim = min(RSD, N - base);
        for (int i = threadIdx.x; i < lim; i += 1024)
            degPart[(size_t)b * N + base + i] = s_deg[i];
        return;
    }
    if (bid < degB + NCH) {                 // ---- cnt histogram (whole N) ----
        unsigned* s_cnt2 = smem;
        const int b = bid - degB;
        const int pairsN = (N + 1) >> 1;
        for (int i = threadIdx.x; i < pairsN; i += 1024) s_cnt2[i] = 0u;
        __syncthreads();
        const int e0 = b * chunk, e1 = min(e0 + chunk, nE);
        for (int e = e0 + (int)threadIdx.x; e < e1; e += 1024) {
            unsigned d = (unsigned)dst[e];
            atomicAdd(&s_cnt2[d >> 1], 1u << ((d & 1) * 16));
        }
        __syncthreads();
        unsigned* cp32 = reinterpret_cast<unsigned*>(cntPart + (size_t)b * N);
        for (int i = threadIdx.x; i < pairsN; i += 1024) cp32[i] = s_cnt2[i];
        return;
    }
    // ---- prepack + x->bf16 ----
    int idx = (bid - degB - NCH) * 1024 + (int)threadIdx.x;
    if (idx < 12 * 4 * 64) {
        int lane = idx & 63;
        int kt = (idx >> 6) & 3;
        int nt = idx >> 8;
        int gate = (nt < 4) ? 0 : (nt < 8) ? 2 : 3;
        int h = (nt & 3) * 16 + (lane & 15);
        int fb = (lane >> 4) * 8;
        short8v v;
#pragma unroll
        for (int j = 0; j < 8; ++j)
            v[j] = f2bf(Wx[((size_t)(gate * 4 + kt) * 32 + fb + j) * 64 + h]);
        *(reinterpret_cast<short8v*>(P) + idx) = v;
        return;
    }
    int i = idx - 12 * 4 * 64;
    if (i >= n4) return;
    const float4 v = *reinterpret_cast<const float4*>(x + (size_t)i * 4);
    short4 rb;
    rb.x = f2bf(v.x); rb.y = f2bf(v.y); rb.z = f2bf(v.z); rb.w = f2bf(v.w);
    *reinterpret_cast<short4*>(xb + (size_t)i * 4) = rb;
}

// merged: reduce partials -> dinv/cnt, block scan, atomic barrier (98 blocks
// co-resident), per-block partial prefix, rowptr + per-chunk offs from LDS.
__global__ __launch_bounds__(NT)
void k_scan_merged(const float* __restrict__ degPart,
                   const unsigned short* __restrict__ cntPart,
                   float* __restrict__ dinv, int* __restrict__ cnt,
                   int* __restrict__ rowptr, int* __restrict__ partials,
                   int* __restrict__ flag, int* __restrict__ offs, int N) {
    __shared__ unsigned s_c[NCH * NT];   // 64KB: per-thread 2-node packed cnt
    __shared__ int sp[NT];
    const int t = threadIdx.x;
    const int n0 = blockIdx.x * (NT * 2) + t * 2;
    float d0 = 0.f, d1 = 0.f;
    int c0 = 0, c1 = 0;
    if (n0 < N) {
#pragma unroll 8
        for (int b = 0; b < NCH; ++b) {
            const float2 dv = *reinterpret_cast<const float2*>(degPart + (size_t)b * N + n0);
            d0 += dv.x; d1 += dv.y;
            unsigned cc = *reinterpret_cast<const unsigned*>(cntPart + (size_t)b * N + n0);
            s_c[b * NT + t] = cc;
            c0 += (int)(cc & 0xFFFFu); c1 += (int)(cc >> 16);
        }
        dinv[n0] = d0 > 0.f ? rsqrtf(d0) : 0.f;
        cnt[n0] = c0;
        if (n0 + 1 < N) {
            dinv[n0 + 1] = d1 > 0.f ? rsqrtf(d1) : 0.f;
            cnt[n0 + 1] = c1;
        } else c1 = 0;
    }
    int cs = c0 + c1;
    sp[t] = cs;
    __syncthreads();
    for (int off = 1; off < NT; off <<= 1) {
        int u = (t >= off) ? sp[t - off] : 0;
        __syncthreads();
        sp[t] += u;
        __syncthreads();
    }
    const int ex = sp[t] - cs;
    const int total = sp[NT - 1];
    __syncthreads();
    if (t == 0) {
        __hip_atomic_store(&partials[blockIdx.x], total, __ATOMIC_RELEASE,
                           __HIP_MEMORY_SCOPE_AGENT);
        __hip_atomic_fetch_add(flag, 1, __ATOMIC_RELEASE, __HIP_MEMORY_SCOPE_AGENT);
        while (__hip_atomic_load(flag, __ATOMIC_RELAXED,
                                 __HIP_MEMORY_SCOPE_AGENT) < (int)gridDim.x)
            __builtin_amdgcn_s_sleep(8);
        __builtin_amdgcn_fence(__ATOMIC_ACQUIRE, "agent");
    }
    __syncthreads();
    int v = (t < (int)blockIdx.x)
                ? __hip_atomic_load(&partials[t], __ATOMIC_RELAXED,
                                    __HIP_MEMORY_SCOPE_AGENT)
                : 0;
    sp[t] = v;
    __syncthreads();
    for (int off = NT / 2; off > 0; off >>= 1) {
        if (t < off) sp[t] += sp[t + off];
        __syncthreads();
    }
    const int prefix = sp[0];
    if (n0 >= N) return;
    const bool has1 = (n0 + 1) < N;
    int s0 = ex + prefix;
    int s1 = has1 ? ex + c0 + prefix : 0;
    rowptr[n0] = s0;
    if (has1) rowptr[n0 + 1] = s1;
#pragma unroll 8
    for (int b = 0; b < NCH; ++b) {
        unsigned cc = s_c[b * NT + t];
        if (has1) {
            *reinterpret_cast<int2*>(offs + (size_t)b * N + n0) = make_int2(s0, s1);
        } else {
            offs[(size_t)b * N + n0] = s0;
        }
        s0 += (int)(cc & 0xFFFFu);
        s1 += (int)(cc >> 16);
    }
}

// counting-sort fill: 3 ranges x 64 chunks, LDS cursor seeded from per-chunk
// offsets; no global atomics, no per-edge offs dependency.
__global__ __launch_bounds__(1024)
void k_fill2(const int* __restrict__ src, const int* __restrict__ dst,
             const float* __restrict__ w, const float* __restrict__ dinv,
             const int* __restrict__ offs, int2* __restrict__ entries,
             int nE, int N) {
    __shared__ int s_cur[RSF];
    const int r = blockIdx.x / NCH, b = blockIdx.x % NCH;
    const int base = r * RSF;
    const int lim = min(RSF, N - base);
    for (int i = threadIdx.x; i < lim; i += 1024)
        s_cur[i] = offs[(size_t)b * N + base + i];
    __syncthreads();
    const int chunk = (nE + NCH - 1) / NCH;
    const int e0 = b * chunk, e1 = min(e0 + chunk, nE);
    for (int e = e0 + (int)threadIdx.x; e < e1; e += 1024) {
        int d = dst[e];
        unsigned dof = (unsigned)(d - base);
        if (dof < RSF) {
            int s = src[e];
            float nv = -dinv[s] * w[e] * dinv[d];
            int pos = atomicAdd(&s_cur[dof], 1);
            entries[pos] = make_int2(s, __float_as_int(nv));
        }
    }
}

__device__ __forceinline__ void bf8_fma(float* acc, ushort8v v, float s) {
#pragma unroll
    for (int j = 0; j < 8; ++j)
        acc[j] = fmaf(s, bf2f(v[j]), acc[j]);
}

// one gather work-item: 16 threads/node (tq feature-slice, qr entry-quarter)
__device__ __forceinline__ void gather_item(
    const unsigned short* __restrict__ tb, const unsigned short* __restrict__ subb,
    short* __restrict__ outb, const int* __restrict__ rowptr,
    const int* __restrict__ cnt, const int2* __restrict__ entries,
    float scale, int idx) {
    int n = idx >> 4, tq = idx & 3, qr = (idx >> 2) & 3;
    int beg = rowptr[n], end = beg + cnt[n];
    float acc0[8] = {0, 0, 0, 0, 0, 0, 0, 0};
    float acc1[8] = {0, 0, 0, 0, 0, 0, 0, 0};
    int i = beg + qr;
    for (; i + 12 < end; i += 16) {
        int2 e0 = entries[i];
        int2 e1 = entries[i + 4];
        int2 e2 = entries[i + 8];
        int2 e3 = entries[i + 12];
        ushort8v v0 = *reinterpret_cast<const ushort8v*>(tb + (size_t)e0.x * 32 + tq * 8);
        ushort8v v1 = *reinterpret_cast<const ushort8v*>(tb + (size_t)e1.x * 32 + tq * 8);
        ushort8v v2 = *reinterpret_cast<const ushort8v*>(tb + (size_t)e2.x * 32 + tq * 8);
        ushort8v v3 = *reinterpret_cast<const ushort8v*>(tb + (size_t)e3.x * 32 + tq * 8);
        bf8_fma(acc0, v0, __int_as_float(e0.y));
        bf8_fma(acc1, v1, __int_as_float(e1.y));
        bf8_fma(acc0, v2, __int_as_float(e2.y));
        bf8_fma(acc1, v3, __int_as_float(e3.y));
    }
    for (; i < end; i += 4) {
        int2 e0 = entries[i];
        ushort8v v0 = *reinterpret_cast<const ushort8v*>(tb + (size_t)e0.x * 32 + tq * 8);
        bf8_fma(acc0, v0, __int_as_float(e0.y));
    }
    float r[8];
#pragma unroll
    for (int j = 0; j < 8; ++j) {
        r[j] = acc0[j] + acc1[j];
        r[j] += __shfl_xor(r[j], 4);
        r[j] += __shfl_xor(r[j], 8);
    }
    if (qr == 0) {
        if (subb) {
            ushort8v sv = *reinterpret_cast<const ushort8v*>(subb + (size_t)n * 32 + tq * 8);
#pragma unroll
            for (int j = 0; j < 8; ++j) r[j] = fmaf(scale, r[j], -bf2f(sv[j]));
        } else {
#pragma unroll
            for (int j = 0; j < 8; ++j) r[j] *= scale;
        }
        short8v rb;
#pragma unroll
        for (int j = 0; j < 8; ++j) rb[j] = f2bf(r[j]);
        *reinterpret_cast<short8v*>(outb + (size_t)n * 32 + tq * 8) = rb;
    }
}

// fused gather1 + barrier + gather2. Low-VGPR phase pair only (no MFMA).
// launch_bounds(256,8) caps VGPR at 64 -> 8 blocks/CU -> 2048 co-resident.
__global__ __launch_bounds__(NT12, 8)
void k_gather12(const short* __restrict__ xb, short* __restrict__ Tx1b,
                short* __restrict__ Tx2b,
                const int* __restrict__ rowptr, const int* __restrict__ cnt,
                const int2* __restrict__ entries, int* __restrict__ flag, int N) {
    const int stride = G12 * NT12;
    const int tid0 = blockIdx.x * NT12 + (int)threadIdx.x;
    const unsigned short* xbu = reinterpret_cast<const unsigned short*>(xb);

    for (int idx = tid0; idx < N * 16; idx += stride)
        gather_item(xbu, nullptr, Tx1b, rowptr, cnt, entries, 1.f, idx);
    gbar(flag, G12);
    for (int idx = tid0; idx < N * 16; idx += stride)
        gather_item(reinterpret_cast<const unsigned short*>(Tx1b), xbu, Tx2b,
                    rowptr, cnt, entries, 2.f, idx);
}

__device__ __forceinline__ float sigf(float x) {
    return __builtin_amdgcn_rcpf(1.f + __builtin_amdgcn_exp2f(-1.4426950408889634f * x));
}
__device__ __forceinline__ float tanhf_fast(float x) {
    float e = __builtin_amdgcn_exp2f(2.8853900817779268f * x);
    return 1.f - 2.f * __builtin_amdgcn_rcpf(e + 1.f);
}

// fused gather3 + MFMA gates GEMM + LSTM pointwise + linear head.
__global__ __launch_bounds__(256)
void k_final_g3(const short* __restrict__ xb, const short* __restrict__ t1b,
                const unsigned short* __restrict__ t2b,
                const short* __restrict__ P,
                const int* __restrict__ rowptr, const int* __restrict__ cnt,
                const int2* __restrict__ entries,
                const float* __restrict__ bx, const float* __restrict__ bh,
                const float* __restrict__ wc, const float* __restrict__ bg,
                const float* __restrict__ lin_w, const float* __restrict__ lin_b,
                float* __restrict__ out, int N) {
    const int wave = threadIdx.x >> 6, lane = threadIdx.x & 63;
    const int nb = blockIdx.x * 64 + wave * 16;
    const int rc = min(nb + (lane & 15), N - 1);
    const int ko = (lane >> 4) * 8;

    int beg = rowptr[rc], end = beg + cnt[rc];
    float acc0[8] = {0, 0, 0, 0, 0, 0, 0, 0};
    float acc1[8] = {0, 0, 0, 0, 0, 0, 0, 0};
    int i = beg;
    for (; i + 3 < end; i += 4) {
        int2 e0 = entries[i];
        int2 e1 = entries[i + 1];
        int2 e2 = entries[i + 2];
        int2 e3 = entries[i + 3];
        ushort8v v0 = *reinterpret_cast<const ushort8v*>(t2b + (size_t)e0.x * 32 + ko);
        ushort8v v1 = *reinterpret_cast<const ushort8v*>(t2b + (size_t)e1.x * 32 + ko);
        ushort8v v2 = *reinterpret_cast<const ushort8v*>(t2b + (size_t)e2.x * 32 + ko);
        ushort8v v3 = *reinterpret_cast<const ushort8v*>(t2b + (size_t)e3.x * 32 + ko);
        bf8_fma(acc0, v0, __int_as_float(e0.y));
        bf8_fma(acc1, v1, __int_as_float(e1.y));
        bf8_fma(acc0, v2, __int_as_float(e2.y));
        bf8_fma(acc1, v3, __int_as_float(e3.y));
    }
    for (; i < end; ++i) {
        int2 e0 = entries[i];
        ushort8v v0 = *reinterpret_cast<const ushort8v*>(t2b + (size_t)e0.x * 32 + ko);
        bf8_fma(acc0, v0, __int_as_float(e0.y));
    }

    short8v A0 = *reinterpret_cast<const short8v*>(xb  + (size_t)rc * 32 + ko);
    short8v A1 = *reinterpret_cast<const short8v*>(t1b + (size_t)rc * 32 + ko);
    short8v A2 = *reinterpret_cast<const short8v*>(
        reinterpret_cast<const short*>(t2b) + (size_t)rc * 32 + ko);
    short8v A3;
#pragma unroll
    for (int j = 0; j < 8; ++j)   // Tx3 = 2*prop(Tx2) - Tx1
        A3[j] = f2bf(2.f * (acc0[j] + acc1[j]) - bf2f((unsigned short)A1[j]));

    const short8v* Pv = reinterpret_cast<const short8v*>(P);
    f32x4 acc[12];
#pragma unroll
    for (int nt = 0; nt < 12; ++nt) {
        const short8v* Pb = Pv + (size_t)nt * 4 * 64 + lane;
        f32x4 a = {0.f, 0.f, 0.f, 0.f};
        a = __builtin_amdgcn_mfma_f32_16x16x32_bf16(A0, Pb[0],   a, 0, 0, 0);
        a = __builtin_amdgcn_mfma_f32_16x16x32_bf16(A1, Pb[64],  a, 0, 0, 0);
        a = __builtin_amdgcn_mfma_f32_16x16x32_bf16(A2, Pb[128], a, 0, 0, 0);
        a = __builtin_amdgcn_mfma_f32_16x16x32_bf16(A3, Pb[192], a, 0, 0, 0);
        acc[nt] = a;
    }

    const int hq = lane & 15;
    const int ng = lane >> 4;
    const float lb = lin_b[0];
    float p[4] = {0.f, 0.f, 0.f, 0.f};
#pragma unroll
    for (int ht = 0; ht < 4; ++ht) {
        int h = ht * 16 + hq;
        float bI = bx[h] + bh[h] + bg[h];
        float bC = bx[128 + h] + bh[128 + h] + bg[128 + h];
        float bO = bx[192 + h] + bh[192 + h] + bg[192 + h];
        float w2 = wc[128 + h];
        float lw = lin_w[h];
#pragma unroll
        for (int r = 0; r < 4; ++r) {
            float I = sigf(acc[ht][r] + bI);
            float T = tanhf_fast(acc[4 + ht][r] + bC);
            float C = I * T;
            float O = sigf(acc[8 + ht][r] + bO + w2 * C);
            float H = O * tanhf_fast(C);
            p[r] = fmaf(H, lw, p[r]);
        }
    }
#pragma unroll
    for (int r = 0; r < 4; ++r) {
        float v = p[r];
        v += __shfl_xor(v, 1);
        v += __shfl_xor(v, 2);
        v += __shfl_xor(v, 4);
        v += __shfl_xor(v, 8);
        if (hq == 0) {
            int n = nb + ng * 4 + r;
            if (n < N) out[n] = v + lb;
        }
    }
}

extern "C" void kernel_launch(void* const* d_in, const int* in_sizes, int n_in,
                              void* d_out, int out_size, void* d_ws, size_t ws_size,
                              hipStream_t stream) {
    const float* x   = (const float*)d_in[0];
    const int*   ei  = (const int*)d_in[1];
    const float* ew  = (const float*)d_in[2];
    const float* Wx  = (const float*)d_in[3];
    const float* bx  = (const float*)d_in[4];
    // d_in[5] = Wh (unused: zero initial state)
    const float* bh  = (const float*)d_in[6];
    const float* wcp = (const float*)d_in[7];
    const float* bg  = (const float*)d_in[8];
    const float* lw  = (const float*)d_in[9];
    const float* lb  = (const float*)d_in[10];
    float* out = (float*)d_out;

    const int N  = in_sizes[0] / 32;
    const int nE = in_sizes[2];
    const int* src = ei;
    const int* dst = ei + nE;

    char* ws = (char*)d_ws;
    size_t off = 0;
    float* dinv    = (float*)(ws + off); off += (size_t)N * 4;
    int*   cnt     = (int*)(ws + off);   off += (size_t)N * 4;
    int*   rowptr  = (int*)(ws + off);   off += (size_t)N * 4;
    int*   partials= (int*)(ws + off);   off += 1024 * 4;
    int*   flags   = (int*)(ws + off);   off += 256;   // flags[0]=scan, flags[1]=g12
    short* P       = (short*)(ws + off); off += 12 * 4 * 64 * 8 * 2;
    int2*  entries = (int2*)(ws + off);  off += (size_t)nE * 8;
    float* degPart = (float*)(ws + off); off += (size_t)NCH * N * 4;  // aliased as offs
    unsigned short* cntPart = (unsigned short*)(ws + off); off += (size_t)NCH * N * 2;
    short* xbuf    = (short*)(ws + off); off += (size_t)N * 32 * 2;
    short* Tx1b    = (short*)(ws + off); off += (size_t)N * 32 * 2;
    short* Tx2b    = (short*)(ws + off); off += (size_t)N * 32 * 2;

    int* offs = (int*)degPart;  // degPart dead after k_scan_merged phase 1

    const int nRangeD = (N + RSD - 1) / RSD;
    const int degB = nRangeD * NCH;
    const int n4 = N * 8;
    const int xbB = (12 * 4 * 64 + n4 + 1023) / 1024;
    const int nb2 = (N + NT * 2 - 1) / (NT * 2);   // 98 blocks (co-resident)
    const int nRangeF = (N + RSF - 1) / RSF;

    k_front<<<degB + NCH + xbB, 1024, 0, stream>>>(src, dst, ew, degPart, cntPart,
                                                   Wx, P, x, xbuf, flags,
                                                   nE, N, degB, n4);
    k_scan_merged<<<nb2, NT, 0, stream>>>(degPart, cntPart, dinv, cnt, rowptr,
                                          partials, &flags[0], offs, N);
    k_fill2<<<nRangeF * NCH, 1024, 0, stream>>>(src, dst, ew, dinv, offs,
                                                entries, nE, N);
    k_gather12<<<G12, NT12, 0, stream>>>(xbuf, Tx1b, Tx2b, rowptr, cnt, entries,
                                         &flags[1], N);
    const int fb = (N + 63) / 64;
    k_final_g3<<<fb, NT, 0, stream>>>(xbuf, Tx1b, (const unsigned short*)Tx2b, P,
                                      rowptr, cnt, entries, bx, bh, wcp, bg,
                                      lw, lb, out, N);
}

// Round 18
// 100.043 us; speedup vs baseline: 3.0842x; 3.0842x over previous
//
#include <hip/hip_runtime.h>
#include <math.h>

// GConvLSTM single step from zero state + linear head.
// H=C=0 initially => cheb_conv(H)=bh[g], F-gate irrelevant.
//   I = sigmoid(chebX_0 + b*), T = tanh(chebX_2 + b*), C = I*T,
//   O = sigmoid(chebX_3 + b* + wc2*C), out = (O*tanh(C)) @ lin_w + lin_b
//
// R2 pull-CSR; R3 hw transcendentals; R7 zero global atomics;
// R8 bf16 MFMA; R9 bf16 recursion; R10 fused gather3; R11 full-CU scans;
// R12 merged scan w/ atomic barrier (98 blocks: cheap); R13/R14 operand-split
// front + 3-range fill.
// R15-R17 (FAILED) mapped the in-kernel-barrier cost curve: 98 blocks free,
//      192 OK, 2048 = 230us of coherence-point spin. Gathers need >2000
//      blocks for latency hiding -> they must stay separate dispatches.
// R18: R14 pipeline exactly; only safe R17 piece kept (flags zeroed in
//      k_front, no memset dispatch). 6 dispatches, serialization floor.

#define NT 256
#define NCH 64      // edge chunks
#define RSD 25600   // deg hist range: 25600*4B = 100KB LDS
#define RSF 20480   // fill range: 80KB LDS -> 2 blocks/CU, 192 blocks

typedef __attribute__((ext_vector_type(8))) short short8v;
typedef __attribute__((ext_vector_type(8))) unsigned short ushort8v;
typedef __attribute__((ext_vector_type(4))) float f32x4;

__device__ __forceinline__ short f2bf(float f) {
    unsigned u = __float_as_uint(f);
    u += 0x7FFFu + ((u >> 16) & 1u);   // round-to-nearest-even
    return (short)(u >> 16);
}
__device__ __forceinline__ float bf2f(unsigned short b) {
    return __uint_as_float((unsigned)b << 16);
}

// role A (bid < degB): deg f32 LDS histogram (2 ranges x 64 chunks).
// role B (next 64): cnt u16-packed whole-N histogram. role C: prepack + xb.
// Block 0 zeroes the scan barrier flag (visible downstream by stream order).
__global__ __launch_bounds__(1024)
void k_front(const int* __restrict__ src, const int* __restrict__ dst,
             const float* __restrict__ w, float* __restrict__ degPart,
             unsigned short* __restrict__ cntPart,
             const float* __restrict__ Wx, short* __restrict__ P,
             const float* __restrict__ x, short* __restrict__ xb,
             int* __restrict__ flags, int nE, int N, int degB, int n4) {
    __shared__ unsigned smem[RSD];   // 100KB, role-dependent view
    const int bid = blockIdx.x;
    const int chunk = (nE + NCH - 1) / NCH;
    if (bid == 0 && threadIdx.x < 2) flags[threadIdx.x] = 0;

    if (bid < degB) {                       // ---- deg histogram ----
        float* s_deg = reinterpret_cast<float*>(smem);
        const int r = bid / NCH, b = bid % NCH;
        const int base = r * RSD;
        for (int i = threadIdx.x; i < RSD; i += 1024) s_deg[i] = 0.f;
        __syncthreads();
        const int e0 = b * chunk, e1 = min(e0 + chunk, nE);
        for (int e = e0 + (int)threadIdx.x; e < e1; e += 1024) {
            unsigned so = (unsigned)(src[e] - base);
            if (so < RSD) atomicAdd(&s_deg[so], w[e]);
        }
        __syncthreads();
        const int lim = min(RSD, N - base);
        for (int i = threadIdx.x; i < lim; i += 1024)
            degPart[(size_t)b * N + base + i] = s_deg[i];
        return;
    }
    if (bid < degB + NCH) {                 // ---- cnt histogram (whole N) ----
        unsigned* s_cnt2 = smem;
        const int b = bid - degB;
        const int pairsN = (N + 1) >> 1;
        for (int i = threadIdx.x; i < pairsN; i += 1024) s_cnt2[i] = 0u;
        __syncthreads();
        const int e0 = b * chunk, e1 = min(e0 + chunk, nE);
        for (int e = e0 + (int)threadIdx.x; e < e1; e += 1024) {
            unsigned d = (unsigned)dst[e];
            atomicAdd(&s_cnt2[d >> 1], 1u << ((d & 1) * 16));
        }
        __syncthreads();
        unsigned* cp32 = reinterpret_cast<unsigned*>(cntPart + (size_t)b * N);
        for (int i = threadIdx.x; i < pairsN; i += 1024) cp32[i] = s_cnt2[i];
        return;
    }
    // ---- prepack + x->bf16 ----
    int idx = (bid - degB - NCH) * 1024 + (int)threadIdx.x;
    if (idx < 12 * 4 * 64) {
        int lane = idx & 63;
        int kt = (idx >> 6) & 3;
        int nt = idx >> 8;
        int gate = (nt < 4) ? 0 : (nt < 8) ? 2 : 3;
        int h = (nt & 3) * 16 + (lane & 15);
        int fb = (lane >> 4) * 8;
        short8v v;
#pragma unroll
        for (int j = 0; j < 8; ++j)
            v[j] = f2bf(Wx[((size_t)(gate * 4 + kt) * 32 + fb + j) * 64 + h]);
        *(reinterpret_cast<short8v*>(P) + idx) = v;
        return;
    }
    int i = idx - 12 * 4 * 64;
    if (i >= n4) return;
    const float4 v = *reinterpret_cast<const float4*>(x + (size_t)i * 4);
    short4 rb;
    rb.x = f2bf(v.x); rb.y = f2bf(v.y); rb.z = f2bf(v.z); rb.w = f2bf(v.w);
    *reinterpret_cast<short4*>(xb + (size_t)i * 4) = rb;
}

// merged: reduce partials -> dinv/cnt, block scan, atomic barrier (98 blocks
// co-resident: proven-cheap arrival count), per-block partial prefix,
// rowptr + per-chunk offs from LDS-cached cnt.
__global__ __launch_bounds__(NT)
void k_scan_merged(const float* __restrict__ degPart,
                   const unsigned short* __restrict__ cntPart,
                   float* __restrict__ dinv, int* __restrict__ cnt,
                   int* __restrict__ rowptr, int* __restrict__ partials,
                   int* __restrict__ flag, int* __restrict__ offs, int N) {
    __shared__ unsigned s_c[NCH * NT];   // 64KB: per-thread 2-node packed cnt
    __shared__ int sp[NT];
    const int t = threadIdx.x;
    const int n0 = blockIdx.x * (NT * 2) + t * 2;
    float d0 = 0.f, d1 = 0.f;
    int c0 = 0, c1 = 0;
    if (n0 < N) {
#pragma unroll 8
        for (int b = 0; b < NCH; ++b) {
            const float2 dv = *reinterpret_cast<const float2*>(degPart + (size_t)b * N + n0);
            d0 += dv.x; d1 += dv.y;
            unsigned cc = *reinterpret_cast<const unsigned*>(cntPart + (size_t)b * N + n0);
            s_c[b * NT + t] = cc;
            c0 += (int)(cc & 0xFFFFu); c1 += (int)(cc >> 16);
        }
        dinv[n0] = d0 > 0.f ? rsqrtf(d0) : 0.f;
        cnt[n0] = c0;
        if (n0 + 1 < N) {
            dinv[n0 + 1] = d1 > 0.f ? rsqrtf(d1) : 0.f;
            cnt[n0 + 1] = c1;
        } else c1 = 0;
    }
    int cs = c0 + c1;
    sp[t] = cs;
    __syncthreads();
    for (int off = 1; off < NT; off <<= 1) {
        int u = (t >= off) ? sp[t - off] : 0;
        __syncthreads();
        sp[t] += u;
        __syncthreads();
    }
    const int ex = sp[t] - cs;
    const int total = sp[NT - 1];
    __syncthreads();
    if (t == 0) {
        __hip_atomic_store(&partials[blockIdx.x], total, __ATOMIC_RELEASE,
                           __HIP_MEMORY_SCOPE_AGENT);
        __hip_atomic_fetch_add(flag, 1, __ATOMIC_RELEASE, __HIP_MEMORY_SCOPE_AGENT);
        while (__hip_atomic_load(flag, __ATOMIC_RELAXED,
                                 __HIP_MEMORY_SCOPE_AGENT) < (int)gridDim.x)
            __builtin_amdgcn_s_sleep(8);
        __builtin_amdgcn_fence(__ATOMIC_ACQUIRE, "agent");
    }
    __syncthreads();
    int v = (t < (int)blockIdx.x)
                ? __hip_atomic_load(&partials[t], __ATOMIC_RELAXED,
                                    __HIP_MEMORY_SCOPE_AGENT)
                : 0;
    sp[t] = v;
    __syncthreads();
    for (int off = NT / 2; off > 0; off >>= 1) {
        if (t < off) sp[t] += sp[t + off];
        __syncthreads();
    }
    const int prefix = sp[0];
    if (n0 >= N) return;
    const bool has1 = (n0 + 1) < N;
    int s0 = ex + prefix;
    int s1 = has1 ? ex + c0 + prefix : 0;
    rowptr[n0] = s0;
    if (has1) rowptr[n0 + 1] = s1;
#pragma unroll 8
    for (int b = 0; b < NCH; ++b) {
        unsigned cc = s_c[b * NT + t];
        if (has1) {
            *reinterpret_cast<int2*>(offs + (size_t)b * N + n0) = make_int2(s0, s1);
        } else {
            offs[(size_t)b * N + n0] = s0;
        }
        s0 += (int)(cc & 0xFFFFu);
        s1 += (int)(cc >> 16);
    }
}

// counting-sort fill: 3 ranges x 64 chunks, LDS cursor seeded from per-chunk
// offsets; no global atomics, no per-edge offs dependency.
__global__ __launch_bounds__(1024)
void k_fill2(const int* __restrict__ src, const int* __restrict__ dst,
             const float* __restrict__ w, const float* __restrict__ dinv,
             const int* __restrict__ offs, int2* __restrict__ entries,
             int nE, int N) {
    __shared__ int s_cur[RSF];
    const int r = blockIdx.x / NCH, b = blockIdx.x % NCH;
    const int base = r * RSF;
    const int lim = min(RSF, N - base);
    for (int i = threadIdx.x; i < lim; i += 1024)
        s_cur[i] = offs[(size_t)b * N + base + i];
    __syncthreads();
    const int chunk = (nE + NCH - 1) / NCH;
    const int e0 = b * chunk, e1 = min(e0 + chunk, nE);
    for (int e = e0 + (int)threadIdx.x; e < e1; e += 1024) {
        int d = dst[e];
        unsigned dof = (unsigned)(d - base);
        if (dof < RSF) {
            int s = src[e];
            float nv = -dinv[s] * w[e] * dinv[d];
            int pos = atomicAdd(&s_cur[dof], 1);
            entries[pos] = make_int2(s, __float_as_int(nv));
        }
    }
}

__device__ __forceinline__ void bf8_fma(float* acc, ushort8v v, float s) {
#pragma unroll
    for (int j = 0; j < 8; ++j)
        acc[j] = fmaf(s, bf2f(v[j]), acc[j]);
}

// bf16-table gather, f32 accumulate, bf16 out. 16 threads/node:
// tq = idx&3 (8-feature slice), qr = (idx>>2)&3 (entry quarter, stride 4).
__global__ __launch_bounds__(256)
void k_gather_bf(const unsigned short* __restrict__ tb,
                 const unsigned short* __restrict__ subb,
                 short* __restrict__ outb,
                 const int* __restrict__ rowptr, const int* __restrict__ cnt,
                 const int2* __restrict__ entries, float scale, int N) {
    int idx = blockIdx.x * blockDim.x + threadIdx.x;
    if (idx >= N * 16) return;
    int n = idx >> 4, tq = idx & 3, qr = (idx >> 2) & 3;
    int beg = rowptr[n], end = beg + cnt[n];
    float acc0[8] = {0, 0, 0, 0, 0, 0, 0, 0};
    float acc1[8] = {0, 0, 0, 0, 0, 0, 0, 0};
    int i = beg + qr;
    for (; i + 12 < end; i += 16) {
        int2 e0 = entries[i];
        int2 e1 = entries[i + 4];
        int2 e2 = entries[i + 8];
        int2 e3 = entries[i + 12];
        ushort8v v0 = *reinterpret_cast<const ushort8v*>(tb + (size_t)e0.x * 32 + tq * 8);
        ushort8v v1 = *reinterpret_cast<const ushort8v*>(tb + (size_t)e1.x * 32 + tq * 8);
        ushort8v v2 = *reinterpret_cast<const ushort8v*>(tb + (size_t)e2.x * 32 + tq * 8);
        ushort8v v3 = *reinterpret_cast<const ushort8v*>(tb + (size_t)e3.x * 32 + tq * 8);
        bf8_fma(acc0, v0, __int_as_float(e0.y));
        bf8_fma(acc1, v1, __int_as_float(e1.y));
        bf8_fma(acc0, v2, __int_as_float(e2.y));
        bf8_fma(acc1, v3, __int_as_float(e3.y));
    }
    for (; i < end; i += 4) {
        int2 e0 = entries[i];
        ushort8v v0 = *reinterpret_cast<const ushort8v*>(tb + (size_t)e0.x * 32 + tq * 8);
        bf8_fma(acc0, v0, __int_as_float(e0.y));
    }
    float r[8];
#pragma unroll
    for (int j = 0; j < 8; ++j) {
        r[j] = acc0[j] + acc1[j];
        r[j] += __shfl_xor(r[j], 4);
        r[j] += __shfl_xor(r[j], 8);
    }
    if (qr == 0) {
        if (subb) {
            ushort8v sv = *reinterpret_cast<const ushort8v*>(subb + (size_t)n * 32 + tq * 8);
#pragma unroll
            for (int j = 0; j < 8; ++j) r[j] = fmaf(scale, r[j], -bf2f(sv[j]));
        } else {
#pragma unroll
            for (int j = 0; j < 8; ++j) r[j] *= scale;
        }
        short8v rb;
#pragma unroll
        for (int j = 0; j < 8; ++j) rb[j] = f2bf(r[j]);
        *reinterpret_cast<short8v*>(outb + (size_t)n * 32 + tq * 8) = rb;
    }
}

__device__ __forceinline__ float sigf(float x) {
    return __builtin_amdgcn_rcpf(1.f + __builtin_amdgcn_exp2f(-1.4426950408889634f * x));
}
__device__ __forceinline__ float tanhf_fast(float x) {
    float e = __builtin_amdgcn_exp2f(2.8853900817779268f * x);
    return 1.f - 2.f * __builtin_amdgcn_rcpf(e + 1.f);
}

// fused gather3 + MFMA gates GEMM + LSTM pointwise + linear head.
__global__ __launch_bounds__(256)
void k_final_g3(const short* __restrict__ xb, const short* __restrict__ t1b,
                const unsigned short* __restrict__ t2b,
                const short* __restrict__ P,
                const int* __restrict__ rowptr, const int* __restrict__ cnt,
                const int2* __restrict__ entries,
                const float* __restrict__ bx, const float* __restrict__ bh,
                const float* __restrict__ wc, const float* __restrict__ bg,
                const float* __restrict__ lin_w, const float* __restrict__ lin_b,
                float* __restrict__ out, int N) {
    const int wave = threadIdx.x >> 6, lane = threadIdx.x & 63;
    const int nb = blockIdx.x * 64 + wave * 16;
    const int rc = min(nb + (lane & 15), N - 1);
    const int ko = (lane >> 4) * 8;

    int beg = rowptr[rc], end = beg + cnt[rc];
    float acc0[8] = {0, 0, 0, 0, 0, 0, 0, 0};
    float acc1[8] = {0, 0, 0, 0, 0, 0, 0, 0};
    int i = beg;
    for (; i + 3 < end; i += 4) {
        int2 e0 = entries[i];
        int2 e1 = entries[i + 1];
        int2 e2 = entries[i + 2];
        int2 e3 = entries[i + 3];
        ushort8v v0 = *reinterpret_cast<const ushort8v*>(t2b + (size_t)e0.x * 32 + ko);
        ushort8v v1 = *reinterpret_cast<const ushort8v*>(t2b + (size_t)e1.x * 32 + ko);
        ushort8v v2 = *reinterpret_cast<const ushort8v*>(t2b + (size_t)e2.x * 32 + ko);
        ushort8v v3 = *reinterpret_cast<const ushort8v*>(t2b + (size_t)e3.x * 32 + ko);
        bf8_fma(acc0, v0, __int_as_float(e0.y));
        bf8_fma(acc1, v1, __int_as_float(e1.y));
        bf8_fma(acc0, v2, __int_as_float(e2.y));
        bf8_fma(acc1, v3, __int_as_float(e3.y));
    }
    for (; i < end; ++i) {
        int2 e0 = entries[i];
        ushort8v v0 = *reinterpret_cast<const ushort8v*>(t2b + (size_t)e0.x * 32 + ko);
        bf8_fma(acc0, v0, __int_as_float(e0.y));
    }

    short8v A0 = *reinterpret_cast<const short8v*>(xb  + (size_t)rc * 32 + ko);
    short8v A1 = *reinterpret_cast<const short8v*>(t1b + (size_t)rc * 32 + ko);
    short8v A2 = *reinterpret_cast<const short8v*>(
        reinterpret_cast<const short*>(t2b) + (size_t)rc * 32 + ko);
    short8v A3;
#pragma unroll
    for (int j = 0; j < 8; ++j)   // Tx3 = 2*prop(Tx2) - Tx1
        A3[j] = f2bf(2.f * (acc0[j] + acc1[j]) - bf2f((unsigned short)A1[j]));

    const short8v* Pv = reinterpret_cast<const short8v*>(P);
    f32x4 acc[12];
#pragma unroll
    for (int nt = 0; nt < 12; ++nt) {
        const short8v* Pb = Pv + (size_t)nt * 4 * 64 + lane;
        f32x4 a = {0.f, 0.f, 0.f, 0.f};
        a = __builtin_amdgcn_mfma_f32_16x16x32_bf16(A0, Pb[0],   a, 0, 0, 0);
        a = __builtin_amdgcn_mfma_f32_16x16x32_bf16(A1, Pb[64],  a, 0, 0, 0);
        a = __builtin_amdgcn_mfma_f32_16x16x32_bf16(A2, Pb[128], a, 0, 0, 0);
        a = __builtin_amdgcn_mfma_f32_16x16x32_bf16(A3, Pb[192], a, 0, 0, 0);
        acc[nt] = a;
    }

    const int hq = lane & 15;
    const int ng = lane >> 4;
    const float lb = lin_b[0];
    float p[4] = {0.f, 0.f, 0.f, 0.f};
#pragma unroll
    for (int ht = 0; ht < 4; ++ht) {
        int h = ht * 16 + hq;
        float bI = bx[h] + bh[h] + bg[h];
        float bC = bx[128 + h] + bh[128 + h] + bg[128 + h];
        float bO = bx[192 + h] + bh[192 + h] + bg[192 + h];
        float w2 = wc[128 + h];
        float lw = lin_w[h];
#pragma unroll
        for (int r = 0; r < 4; ++r) {
            float I = sigf(acc[ht][r] + bI);
            float T = tanhf_fast(acc[4 + ht][r] + bC);
            float C = I * T;
            float O = sigf(acc[8 + ht][r] + bO + w2 * C);
            float H = O * tanhf_fast(C);
            p[r] = fmaf(H, lw, p[r]);
        }
    }
#pragma unroll
    for (int r = 0; r < 4; ++r) {
        float v = p[r];
        v += __shfl_xor(v, 1);
        v += __shfl_xor(v, 2);
        v += __shfl_xor(v, 4);
        v += __shfl_xor(v, 8);
        if (hq == 0) {
            int n = nb + ng * 4 + r;
            if (n < N) out[n] = v + lb;
        }
    }
}

extern "C" void kernel_launch(void* const* d_in, const int* in_sizes, int n_in,
                              void* d_out, int out_size, void* d_ws, size_t ws_size,
                              hipStream_t stream) {
    const float* x   = (const float*)d_in[0];
    const int*   ei  = (const int*)d_in[1];
    const float* ew  = (const float*)d_in[2];
    const float* Wx  = (const float*)d_in[3];
    const float* bx  = (const float*)d_in[4];
    // d_in[5] = Wh (unused: zero initial state)
    const float* bh  = (const float*)d_in[6];
    const float* wcp = (const float*)d_in[7];
    const float* bg  = (const float*)d_in[8];
    const float* lw  = (const float*)d_in[9];
    const float* lb  = (const float*)d_in[10];
    float* out = (float*)d_out;

    const int N  = in_sizes[0] / 32;
    const int nE = in_sizes[2];
    const int* src = ei;
    const int* dst = ei + nE;

    char* ws = (char*)d_ws;
    size_t off = 0;
    float* dinv    = (float*)(ws + off); off += (size_t)N * 4;
    int*   cnt     = (int*)(ws + off);   off += (size_t)N * 4;
    int*   rowptr  = (int*)(ws + off);   off += (size_t)N * 4;
    int*   partials= (int*)(ws + off);   off += 1024 * 4;
    int*   flags   = (int*)(ws + off);   off += 256;
    short* P       = (short*)(ws + off); off += 12 * 4 * 64 * 8 * 2;
    int2*  entries = (int2*)(ws + off);  off += (size_t)nE * 8;
    float* degPart = (float*)(ws + off); off += (size_t)NCH * N * 4;  // aliased as offs
    unsigned short* cntPart = (unsigned short*)(ws + off); off += (size_t)NCH * N * 2;
    short* xbuf    = (short*)(ws + off); off += (size_t)N * 32 * 2;
    short* Tx1b    = (short*)(ws + off); off += (size_t)N * 32 * 2;
    short* Tx2b    = (short*)(ws + off); off += (size_t)N * 32 * 2;

    int* offs = (int*)degPart;  // degPart dead after k_scan_merged phase 1

    const int nRangeD = (N + RSD - 1) / RSD;
    const int degB = nRangeD * NCH;
    const int n4 = N * 8;
    const int xbB = (12 * 4 * 64 + n4 + 1023) / 1024;
    const int nb2 = (N + NT * 2 - 1) / (NT * 2);   // 98 blocks (co-resident)
    const int nRangeF = (N + RSF - 1) / RSF;

    k_front<<<degB + NCH + xbB, 1024, 0, stream>>>(src, dst, ew, degPart, cntPart,
                                                   Wx, P, x, xbuf, flags,
                                                   nE, N, degB, n4);
    k_scan_merged<<<nb2, NT, 0, stream>>>(degPart, cntPart, dinv, cnt, rowptr,
                                          partials, &flags[0], offs, N);
    k_fill2<<<nRangeF * NCH, 1024, 0, stream>>>(src, dst, ew, dinv, offs,
                                                entries, nE, N);

    const int gb = (N * 16 + NT - 1) / NT;
    k_gather_bf<<<gb, NT, 0, stream>>>((const unsigned short*)xbuf, nullptr,
                                       Tx1b, rowptr, cnt, entries, 1.f, N);
    k_gather_bf<<<gb, NT, 0, stream>>>((const unsigned short*)Tx1b,
                                       (const unsigned short*)xbuf,
                                       Tx2b, rowptr, cnt, entries, 2.f, N);

    const int fb = (N + 63) / 64;
    k_final_g3<<<fb, NT, 0, stream>>>(xbuf, Tx1b, (const unsigned short*)Tx2b, P,
                                      rowptr, cnt, entries, bx, bh, wcp, bg,
                                      lw, lb, out, N);
}